// Round 3
// baseline (170.102 us; speedup 1.0000x reference)
//
#include <hip/hip_runtime.h>
#include <stdint.h>

// MipRayMarcher2: NeuS-style alpha compositing.
// R3: persistent double-buffered DMA pipeline.
//
// R0/R1/R2 all landed at ~50 us with every pipe idle (HBM 21%, VALU 13%) and
// identical FETCH/WRITE: the invariant is the in-flight DUTY CYCLE, not load
// issue width. Each block did load -> vmcnt(0) drain -> compute -> exit, so
// average outstanding bytes/CU sat at the edge of the BW*latency product
// (~4.4 MB chip-wide) -> ~3 TB/s request throughput, latency-bound.
//
// This version: 512 blocks (exactly 2/CU resident), each streams 8 tiles of
// 16 rays through 2 x 33 KB LDS buffers. Tile i+1's global_load_lds DMAs are
// issued BEFORE computing tile i; the main loop never drains vmcnt to 0 —
// each wave waits a COUNTED vmcnt (its own chunk count) then raw s_barrier
// (wait-then-barrier makes per-wave retirement collective). Steady state keeps
// ~33 KB/block outstanding continuously (~17 MB chip-wide, 4x BW*latency).

static constexpr int NRAYS = 65536;          // B*R = 4*16384
static constexpr int SM = 47;
static constexpr int OFF_DEPTH  = NRAYS * 3;             // 196608
static constexpr int OFF_W      = OFF_DEPTH + NRAYS;     // 262144
static constexpr int OFF_NORMAL = OFF_W + NRAYS * SM;    // 3342336

static constexpr int TILES_PER_BLOCK = 8;    // 4096 tiles / 512 blocks
static constexpr int NBLOCKS = 512;          // = 2 per CU, all resident

// Per-buffer LDS layout (bytes). colors/normals/reals: 16*48*3*4 = 9216 B
// each; sdf/depth: 16*48*4 = 3072 B each. Buffer = 33792 B; two buffers.
static constexpr int LB_COL = 0;
static constexpr int LB_NRM = 9216;
static constexpr int LB_RNM = 18432;
static constexpr int LB_SDF = 27648;
static constexpr int LB_DEP = 30720;
static constexpr int LDS_BYTES = 33792;      // one buffer
// float-index views
static constexpr int LF_COL = LB_COL / 4;
static constexpr int LF_NRM = LB_NRM / 4;
static constexpr int LF_RNM = LB_RNM / 4;
static constexpr int LF_SDF = LB_SDF / 4;
static constexpr int LF_DEP = LB_DEP / 4;

struct F3 { float x, y, z; };

// DPP move: dst[i] = src[mapped lane in 16-lane row]; invalid lanes keep `old`.
template <int CTRL>
__device__ __forceinline__ float dpp_mov(float x, float old) {
    return __builtin_bit_cast(float,
        __builtin_amdgcn_update_dpp(__builtin_bit_cast(int, old),
                                    __builtin_bit_cast(int, x),
                                    CTRL, 0xF, 0xF, false));
}
#define ROW_SHR(n) (0x110 + (n))
#define ROW_ROR(n) (0x120 + (n))

__device__ __forceinline__ float row_sum16(float x) {
    x += dpp_mov<ROW_ROR(8)>(x, 0.0f);
    x += dpp_mov<ROW_ROR(4)>(x, 0.0f);
    x += dpp_mov<ROW_ROR(2)>(x, 0.0f);
    x += dpp_mov<ROW_ROR(1)>(x, 0.0f);
    return x;
}

// Async DMA: 64 lanes x 16 B = 1 KB, global (per-lane addr) -> LDS
// (wave-uniform base; HW adds lane*16). No destination VGPRs; counts vmcnt.
__device__ __forceinline__ void dma16(char* lds_base, uint32_t lds_off, const char* g) {
    __builtin_amdgcn_global_load_lds(
        (const __attribute__((address_space(1))) void*)g,
        (__attribute__((address_space(3))) void*)(lds_base + lds_off),
        16, 0, 0);
}

__global__ __launch_bounds__(256, 2) void march_kernel(
    const float* __restrict__ colors,
    const float* __restrict__ sdfs,
    const float* __restrict__ depths,
    const float* __restrict__ normals,
    const float* __restrict__ ray_dirs,
    const float* __restrict__ real_normals,
    const float* __restrict__ inv_std_p,
    float* __restrict__ out)
{
    __shared__ __align__(16) char smem[2 * LDS_BYTES];

    const int t    = threadIdx.x;
    const int w    = t >> 6;            // wave id 0..3
    const int lane = t & 63;
    const int g16  = t >> 4;            // ray group within tile (== DPP row)
    const int sl   = t & 15;            // sub-lane within ray group

    // Wave-uniform constants (once).
    const float L2E = 1.4426950408889634f;
    const float inv_std = fminf(fmaxf(__expf(inv_std_p[0] * 10.0f), 1e-6f), 1e6f);
    const float uu = inv_std * (0.5f  * L2E);
    const float qq = inv_std * (0.25f * L2E);

    const int tile0 = blockIdx.x * TILES_PER_BLOCK;
    const uint32_t lo16 = (uint32_t)lane * 16u;

    // Issue all DMA chunks for tile (tile0+i) into buffer bsel.
    auto issue = [&](int i, int bsel) {
        char* dst = smem + bsel * LDS_BYTES;
        const size_t r0 = (size_t)(tile0 + i) * 16;
        if (w == 0) {
            const char* s = (const char*)colors + r0 * 576 + lo16;
#pragma unroll
            for (int k = 0; k < 9; ++k) dma16(dst, LB_COL + k * 1024, s + k * 1024);
        } else if (w == 1) {
            const char* s = (const char*)normals + r0 * 576 + lo16;
#pragma unroll
            for (int k = 0; k < 9; ++k) dma16(dst, LB_NRM + k * 1024, s + k * 1024);
        } else if (w == 2) {
            const char* s = (const char*)real_normals + r0 * 576 + lo16;
#pragma unroll
            for (int k = 0; k < 9; ++k) dma16(dst, LB_RNM + k * 1024, s + k * 1024);
        } else {
            const char* s1 = (const char*)sdfs   + r0 * 192 + lo16;
            const char* s2 = (const char*)depths + r0 * 192 + lo16;
#pragma unroll
            for (int k = 0; k < 3; ++k) dma16(dst, LB_SDF + k * 1024, s1 + k * 1024);
#pragma unroll
            for (int k = 0; k < 3; ++k) dma16(dst, LB_DEP + k * 1024, s2 + k * 1024);
        }
    };

    // Prologue: tile 0 DMA + dir prefetch.
    issue(0, 0);
    F3 dir_cur = ((const F3*)ray_dirs)[tile0 * 16 + g16];
    F3 dir_nxt = dir_cur;

    for (int i = 0; i < TILES_PER_BLOCK; ++i) {
        const int b = i & 1;

        if (i + 1 < TILES_PER_BLOCK) {
            issue(i + 1, b ^ 1);                         // prefetch next tile
            dir_nxt = ((const F3*)ray_dirs)[(tile0 + i + 1) * 16 + g16];
            // Counted wait: allow exactly this wave's NEW chunks to stay in
            // flight; everything older (tile-i chunks) must have retired.
            if (w == 3) asm volatile("s_waitcnt vmcnt(6)" ::: "memory");
            else        asm volatile("s_waitcnt vmcnt(9)" ::: "memory");
        } else {
            asm volatile("s_waitcnt vmcnt(0)" ::: "memory");   // last tile: full drain
        }
        __builtin_amdgcn_s_barrier();      // all waves certified their tile-i DMAs
        asm volatile("" ::: "memory");     // no LDS read hoists above this point

        // ---------------- compute tile i from buffer b ----------------
        const float* sf = (const float*)(smem + b * LDS_BYTES);
        const int ray = (tile0 + i) * 16 + g16;
        const int cfb = g16 * 144 + sl * 9;
        const int sfb = g16 * 48  + sl * 3;

        // Own 3 samples + neighbor's first = 4 contiguous samples.
        float SD[4], DP[4];
#pragma unroll
        for (int c2 = 0; c2 < 4; ++c2) SD[c2] = sf[LF_SDF + sfb + c2];
#pragma unroll
        for (int c2 = 0; c2 < 3; ++c2) DP[c2] = sf[LF_DEP + sfb + c2];
        // (g16==15, sl==15) would read 1 float past the region: clamp (masked).
        DP[3] = sf[LF_DEP + sfb + (((sl < 15) | (g16 < 15)) ? 3 : 2)];

        float C[12], N[12], R[12];   // 4 samples x xyz
#pragma unroll
        for (int q = 0; q < 12; ++q) {
            C[q] = sf[LF_COL + cfb + q];
            N[q] = sf[LF_NRM + cfb + q];
            R[q] = sf[LF_RNM + cfb + q];
        }

        float al[3], tt[3], dsum[3];
#pragma unroll
        for (int j = 0; j < 3; ++j) {
            const float delta = DP[j + 1] - DP[j];
            dsum[j] = DP[j] + DP[j + 1];
            const float ss  = SD[j] + SD[j + 1];
            const float ns0 = N[j * 3 + 0] + N[j * 3 + 3];
            const float ns1 = N[j * 3 + 1] + N[j * 3 + 4];
            const float ns2 = N[j * 3 + 2] + N[j * 3 + 5];

            const float dots = dir_cur.x * ns0 + dir_cur.y * ns1 + dir_cur.z * ns2;
            const float mn   = fminf(dots, 0.0f);
            const float mq   = mn * delta * qq;
            const float base = ss * uu;
            // prev_cdf = 1/(1+exp2(mq-base)); next_cdf = 1/(1+exp2(-(mq+base)))
            const float ep = __builtin_amdgcn_exp2f(mq - base);
            const float pc = __builtin_amdgcn_rcpf(1.0f + ep);
            const float en = __builtin_amdgcn_exp2f(-(mq + base));
            const float nc = __builtin_amdgcn_rcpf(1.0f + en);

            float a = (pc - nc + 1e-5f) * __builtin_amdgcn_rcpf(pc + 1e-5f);
            a = fminf(fmaxf(a, 0.0f), 1.0f);
            const bool valid = (j < 2) | (sl < 15);   // interval 47 does not exist
            if (!valid) a = 0.0f;
            al[j] = a;
            tt[j] = 1.0f - a + 1e-10f;
        }

        // Inclusive multiply-scan over the row (DPP, identity=1).
        float p = tt[0] * tt[1] * tt[2];
        p *= dpp_mov<ROW_SHR(1)>(p, 1.0f);
        p *= dpp_mov<ROW_SHR(2)>(p, 1.0f);
        p *= dpp_mov<ROW_SHR(4)>(p, 1.0f);
        p *= dpp_mov<ROW_SHR(8)>(p, 1.0f);
        const float excl = dpp_mov<ROW_SHR(1)>(p, 1.0f);   // lane 0 -> 1.0

        const float T0 = excl;
        const float T1 = excl * tt[0];
        const float T2 = T1 * tt[1];
        const float w0 = al[0] * T0;
        const float w1 = al[1] * T1;
        const float w2 = al[2] * T2;

        // Weights output (intervals 3*sl .. 3*sl+2).
        const int wbase = OFF_W + ray * SM + sl * 3;
        out[wbase + 0] = w0;
        out[wbase + 1] = w1;
        if (sl < 15) out[wbase + 2] = w2;

        // Per-lane partials (sums are 2x the mids; fixed by 0.5 in epilogue).
        float ws  = w0 + w1 + w2;
        float sc0 = w0 * (C[0] + C[3]) + w1 * (C[3] + C[6]) + w2 * (C[6] + C[9]);
        float sc1 = w0 * (C[1] + C[4]) + w1 * (C[4] + C[7]) + w2 * (C[7] + C[10]);
        float sc2 = w0 * (C[2] + C[5]) + w1 * (C[5] + C[8]) + w2 * (C[8] + C[11]);
        float sdp = w0 * dsum[0] + w1 * dsum[1] + w2 * dsum[2];
        float sr0 = w0 * (R[0] + R[3]) + w1 * (R[3] + R[6]) + w2 * (R[6] + R[9]);
        float sr1 = w0 * (R[1] + R[4]) + w1 * (R[4] + R[7]) + w2 * (R[7] + R[10]);
        float sr2 = w0 * (R[2] + R[5]) + w1 * (R[5] + R[8]) + w2 * (R[8] + R[11]);

        ws  = row_sum16(ws);
        sc0 = row_sum16(sc0);
        sc1 = row_sum16(sc1);
        sc2 = row_sum16(sc2);
        sdp = row_sum16(sdp);
        sr0 = row_sum16(sr0);
        sr1 = row_sum16(sr1);
        sr2 = row_sum16(sr2);

        if (sl == 0) {
            out[ray * 3 + 0] = 0.5f * sc0;
            out[ray * 3 + 1] = 0.5f * sc1;
            out[ray * 3 + 2] = 0.5f * sc2;
            const float hiw = 0.5f * __builtin_amdgcn_rcpf(ws);  // ws >= ~5e-6
            out[OFF_DEPTH + ray] = sdp * hiw;
            out[OFF_NORMAL + ray * 3 + 0] = sr0 * hiw;
            out[OFF_NORMAL + ray * 3 + 1] = sr1 * hiw;
            out[OFF_NORMAL + ray * 3 + 2] = sr2 * hiw;
        }

        // All LDS reads of buffer b consumed before tile i+2 overwrites it.
        asm volatile("s_waitcnt lgkmcnt(0)" ::: "memory");
        __builtin_amdgcn_s_barrier();
        asm volatile("" ::: "memory");

        dir_cur = dir_nxt;
    }
}

extern "C" void kernel_launch(void* const* d_in, const int* in_sizes, int n_in,
                              void* d_out, int out_size, void* d_ws, size_t ws_size,
                              hipStream_t stream) {
    const float* colors       = (const float*)d_in[0];
    const float* sdfs         = (const float*)d_in[1];
    const float* depths       = (const float*)d_in[2];
    const float* normals      = (const float*)d_in[3];
    const float* ray_dirs     = (const float*)d_in[4];
    const float* real_normals = (const float*)d_in[5];
    const float* inv_std_p    = (const float*)d_in[6];
    float* out = (float*)d_out;

    dim3 grid(NBLOCKS);      // 512 blocks x 8 tiles = 4096 tiles = 65536 rays
    dim3 block(256);
    hipLaunchKernelGGL(march_kernel, grid, block, 0, stream,
                       colors, sdfs, depths, normals, ray_dirs, real_normals,
                       inv_std_p, out);
}

// Round 6
// 166.475 us; speedup vs baseline: 1.0218x; 1.0218x over previous
//
#include <hip/hip_runtime.h>

// MipRayMarcher2: NeuS-style alpha compositing.
// 4 rays per wave: 16 lanes/ray, 3 samples per lane (S=48, intervals SM=47).
// ALL cross-lane traffic via DPP row ops (16-lane rows == our ray groups).
//
// R6: R1's proven body (passed, 49us kernel) + ONE keep-alive asm pin that
// reads ALL 36 loaded floats simultaneously. Unlike R1's sched_barrier(0)
// (which changed nothing: VGPR stayed 28, loads stayed serialized), a single
// asm consuming every loaded value forces the register allocator to keep all
// 13 loads live at once -> all loads issued before one waitcnt point.
// This fills the last empty cell of the schedule matrix:
//   R0: reg loads, serialized (28 VGPR)        -> 50us
//   R2: LDS-DMA, 33KB/block all in flight      -> 50us
//   R3: LDS-DMA, persistent double-buffered    -> 53us
//   R6: reg loads, all in flight (this)        -> ?
// If R6 also lands ~50us, the ~3 TB/s service-side ceiling is confirmed
// across every issue structure and the kernel is at its roofline.

static constexpr int NRAYS = 65536;          // B*R = 4*16384
static constexpr int SM = 47;
static constexpr int OFF_DEPTH  = NRAYS * 3;             // 196608
static constexpr int OFF_W      = OFF_DEPTH + NRAYS;     // 262144
static constexpr int OFF_NORMAL = OFF_W + NRAYS * SM;    // 3342336

struct F3 { float x, y, z; };

// DPP move: dst[i] = src[mapped lane in 16-lane row]; invalid lanes keep `old`.
template <int CTRL>
__device__ __forceinline__ float dpp_mov(float x, float old) {
    return __builtin_bit_cast(float,
        __builtin_amdgcn_update_dpp(__builtin_bit_cast(int, old),
                                    __builtin_bit_cast(int, x),
                                    CTRL, 0xF, 0xF, false));
}
#define ROW_SHL1 0x101     // lane i <- lane i+1  (shfl_down 1 within row)
#define ROW_SHR(n) (0x110 + (n))
#define ROW_ROR(n) (0x120 + (n))

__device__ __forceinline__ float row_nbr(float x) {       // value from lane i+1
    return dpp_mov<ROW_SHL1>(x, x);                       // lane15: keep own (masked later)
}

// Sum across the 16-lane row via rotation tree; all lanes end with the total.
__device__ __forceinline__ float row_sum16(float x) {
    x += dpp_mov<ROW_ROR(8)>(x, 0.0f);
    x += dpp_mov<ROW_ROR(4)>(x, 0.0f);
    x += dpp_mov<ROW_ROR(2)>(x, 0.0f);
    x += dpp_mov<ROW_ROR(1)>(x, 0.0f);
    return x;
}

#define PIN3(v) "v"((v).x), "v"((v).y), "v"((v).z)

__global__ __launch_bounds__(256) void march_kernel(
    const float* __restrict__ colors,
    const float* __restrict__ sdfs,
    const float* __restrict__ depths,
    const float* __restrict__ normals,
    const float* __restrict__ ray_dirs,
    const float* __restrict__ real_normals,
    const float* __restrict__ inv_std_p,
    float* __restrict__ out)
{
    const int tid = blockIdx.x * 256 + threadIdx.x;
    const int ray = tid >> 4;                 // 16 lanes per ray
    const int sl  = threadIdx.x & 15;         // sub-lane within ray group (DPP row)

    const int sbase = ray * 16 + sl;          // F3 index into sdfs/depths
    const int cbase = ray * 48 + sl * 3;      // F3 index into colors/normals/real_normals

    // ---------------- Phase 1: issue EVERY global load ----------------
    const float istd_raw = inv_std_p[0];
    const F3 sd3 = ((const F3*)sdfs)[sbase];
    const F3 dp3 = ((const F3*)depths)[sbase];
    const F3 dir = ((const F3*)ray_dirs)[ray];
    F3 n[3], c[3], r[3];
#pragma unroll
    for (int j = 0; j < 3; ++j) n[j] = ((const F3*)normals)[cbase + j];
#pragma unroll
    for (int j = 0; j < 3; ++j) c[j] = ((const F3*)colors)[cbase + j];
#pragma unroll
    for (int j = 0; j < 3; ++j) r[j] = ((const F3*)real_normals)[cbase + j];

    // Single pin reading ALL 36 loaded floats: the register allocator must
    // keep every load's destination live simultaneously, so all 13 loads
    // issue before this point and one waitcnt covers them (true MLP).
    asm volatile("" ::
        PIN3(sd3), PIN3(dp3), PIN3(dir),
        PIN3(n[0]), PIN3(n[1]), PIN3(n[2]),
        PIN3(c[0]), PIN3(c[1]), PIN3(c[2]),
        PIN3(r[0]), PIN3(r[1]), PIN3(r[2]));

    // ---------------- Phase 2: compute ----------------
    const float L2E = 1.4426950408889634f;
    const float inv_std = fminf(fmaxf(__expf(istd_raw * 10.0f), 1e-6f), 1e6f);
    const float uu = inv_std * (0.5f  * L2E);
    const float qq = inv_std * (0.25f * L2E);

    // Neighbor lane's first sample (= this ray-group's sample 3*(sl+1)) via DPP.
    const float sdN = row_nbr(sd3.x);
    const float dpN = row_nbr(dp3.x);
    const float n0N = row_nbr(n[0].x);
    const float n1N = row_nbr(n[0].y);
    const float n2N = row_nbr(n[0].z);

    const float SD[4] = { sd3.x, sd3.y, sd3.z, sdN };
    const float DP[4] = { dp3.x, dp3.y, dp3.z, dpN };
    const float N0[4] = { n[0].x, n[1].x, n[2].x, n0N };
    const float N1[4] = { n[0].y, n[1].y, n[2].y, n1N };
    const float N2[4] = { n[0].z, n[1].z, n[2].z, n2N };

    float al[3], tt[3], dsum[3];
#pragma unroll
    for (int j = 0; j < 3; ++j) {
        const float delta = DP[j + 1] - DP[j];
        dsum[j] = DP[j] + DP[j + 1];
        const float ss  = SD[j] + SD[j + 1];
        const float ns0 = N0[j] + N0[j + 1];
        const float ns1 = N1[j] + N1[j + 1];
        const float ns2 = N2[j] + N2[j + 1];

        const float dots = dir.x * ns0 + dir.y * ns1 + dir.z * ns2;
        const float mn   = fminf(dots, 0.0f);
        const float mq   = mn * delta * qq;
        const float base = ss * uu;
        // prev_cdf = 1/(1+exp2(mq-base)); next_cdf = 1/(1+exp2(-(mq+base)))
        const float ep = __builtin_amdgcn_exp2f(mq - base);
        const float pc = __builtin_amdgcn_rcpf(1.0f + ep);
        const float en = __builtin_amdgcn_exp2f(-(mq + base));
        const float nc = __builtin_amdgcn_rcpf(1.0f + en);

        float a = (pc - nc + 1e-5f) * __builtin_amdgcn_rcpf(pc + 1e-5f);
        a = fminf(fmaxf(a, 0.0f), 1.0f);
        const bool valid = (j < 2) | (sl < 15);   // interval 47 does not exist
        if (!valid) a = 0.0f;
        al[j] = a;
        tt[j] = 1.0f - a + 1e-10f;
    }

    // Inclusive multiply-scan over the row of per-lane products (DPP, identity=1).
    float p = tt[0] * tt[1] * tt[2];
    p *= dpp_mov<ROW_SHR(1)>(p, 1.0f);
    p *= dpp_mov<ROW_SHR(2)>(p, 1.0f);
    p *= dpp_mov<ROW_SHR(4)>(p, 1.0f);
    p *= dpp_mov<ROW_SHR(8)>(p, 1.0f);
    const float excl = dpp_mov<ROW_SHR(1)>(p, 1.0f);   // lane 0 -> 1.0

    const float T0 = excl;
    const float T1 = excl * tt[0];
    const float T2 = T1 * tt[1];
    const float w0 = al[0] * T0;
    const float w1 = al[1] * T1;
    const float w2 = al[2] * T2;

    // Weights output (intervals 3*sl .. 3*sl+2).
    const int wbase = OFF_W + ray * SM + sl * 3;
    out[wbase + 0] = w0;
    out[wbase + 1] = w1;
    if (sl < 15) out[wbase + 2] = w2;

    // Weighted sums over colors / real_normals.
    const float c0N = row_nbr(c[0].x);
    const float c1N = row_nbr(c[0].y);
    const float c2N = row_nbr(c[0].z);
    const float r0N = row_nbr(r[0].x);
    const float r1N = row_nbr(r[0].y);
    const float r2N = row_nbr(r[0].z);

    const float C0[4] = { c[0].x, c[1].x, c[2].x, c0N };
    const float C1[4] = { c[0].y, c[1].y, c[2].y, c1N };
    const float C2[4] = { c[0].z, c[1].z, c[2].z, c2N };
    const float R0[4] = { r[0].x, r[1].x, r[2].x, r0N };
    const float R1[4] = { r[0].y, r[1].y, r[2].y, r1N };
    const float R2[4] = { r[0].z, r[1].z, r[2].z, r2N };

    // Per-lane partials (sums are 2x the mids; fixed by 0.5 in epilogue).
    float ws  = w0 + w1 + w2;
    float sc0 = w0 * (C0[0] + C0[1]) + w1 * (C0[1] + C0[2]) + w2 * (C0[2] + C0[3]);
    float sc1 = w0 * (C1[0] + C1[1]) + w1 * (C1[1] + C1[2]) + w2 * (C1[2] + C1[3]);
    float sc2 = w0 * (C2[0] + C2[1]) + w1 * (C2[1] + C2[2]) + w2 * (C2[2] + C2[3]);
    float sdp = w0 * dsum[0] + w1 * dsum[1] + w2 * dsum[2];
    float sr0 = w0 * (R0[0] + R0[1]) + w1 * (R0[1] + R0[2]) + w2 * (R0[2] + R0[3]);
    float sr1 = w0 * (R1[0] + R1[1]) + w1 * (R1[1] + R1[2]) + w2 * (R1[2] + R1[3]);
    float sr2 = w0 * (R2[0] + R2[1]) + w1 * (R2[1] + R2[2]) + w2 * (R2[2] + R2[3]);

    ws  = row_sum16(ws);
    sc0 = row_sum16(sc0);
    sc1 = row_sum16(sc1);
    sc2 = row_sum16(sc2);
    sdp = row_sum16(sdp);
    sr0 = row_sum16(sr0);
    sr1 = row_sum16(sr1);
    sr2 = row_sum16(sr2);

    if (sl == 0) {
        out[ray * 3 + 0] = 0.5f * sc0;
        out[ray * 3 + 1] = 0.5f * sc1;
        out[ray * 3 + 2] = 0.5f * sc2;
        const float hiw = 0.5f * __builtin_amdgcn_rcpf(ws);  // ws >= ~5e-6 always
        out[OFF_DEPTH + ray] = sdp * hiw;
        out[OFF_NORMAL + ray * 3 + 0] = sr0 * hiw;
        out[OFF_NORMAL + ray * 3 + 1] = sr1 * hiw;
        out[OFF_NORMAL + ray * 3 + 2] = sr2 * hiw;
    }
}

extern "C" void kernel_launch(void* const* d_in, const int* in_sizes, int n_in,
                              void* d_out, int out_size, void* d_ws, size_t ws_size,
                              hipStream_t stream) {
    const float* colors       = (const float*)d_in[0];
    const float* sdfs         = (const float*)d_in[1];
    const float* depths       = (const float*)d_in[2];
    const float* normals      = (const float*)d_in[3];
    const float* ray_dirs     = (const float*)d_in[4];
    const float* real_normals = (const float*)d_in[5];
    const float* inv_std_p    = (const float*)d_in[6];
    float* out = (float*)d_out;

    dim3 grid(NRAYS * 16 / 256);   // 4096 blocks
    dim3 block(256);
    hipLaunchKernelGGL(march_kernel, grid, block, 0, stream,
                       colors, sdfs, depths, normals, ray_dirs, real_normals,
                       inv_std_p, out);
}